// Round 1
// baseline (350.844 us; speedup 1.0000x reference)
//
#include <hip/hip_runtime.h>
#include <hip/hip_bf16.h>
#include <math.h>

#define N_COLS 2048   // N
#define N_ROWS 128    // n
#define KW     32     // W columns (m=30 + p=2)
#define WST    36     // LDS row stride for W (16B-aligned rows, low bank aliasing)
#define COLSTR 132    // stride of one colbuf buffer

// ---------------- transpose kernels (gather efficiency) ----------------
__global__ void transpose_y_kernel(const float* __restrict__ Y, float* __restrict__ Yt) {
  __shared__ float tile[32][33];
  const int bx = blockIdx.x, by = blockIdx.y;
  const int tx = threadIdx.x, ty = threadIdx.y;
#pragma unroll
  for (int q = 0; q < 4; ++q)
    tile[ty + 8 * q][tx] = Y[(by * 32 + ty + 8 * q) * N_COLS + bx * 32 + tx];
  __syncthreads();
#pragma unroll
  for (int q = 0; q < 4; ++q)
    Yt[(bx * 32 + ty + 8 * q) * N_ROWS + by * 32 + tx] = tile[tx][ty + 8 * q];
}

__global__ void transpose_x_kernel(const float2* __restrict__ X, float2* __restrict__ Xt) {
  __shared__ float2 tile[32][33];
  const int bx = blockIdx.x, by = blockIdx.y;
  const int tx = threadIdx.x, ty = threadIdx.y;
#pragma unroll
  for (int q = 0; q < 4; ++q)
    tile[ty + 8 * q][tx] = X[(by * 32 + ty + 8 * q) * N_COLS + bx * 32 + tx];
  __syncthreads();
#pragma unroll
  for (int q = 0; q < 4; ++q)
    Xt[(bx * 32 + ty + 8 * q) * N_ROWS + by * 32 + tx] = tile[tx][ty + 8 * q];
}

// ---------------- fused Cholesky step (register-resident G) ----------------
// Thread (ti,tj) owns G[ti+16a][tj+16c], a,c in [0,8). One barrier per step.
// colbuf holds the RAW current column (double buffered by k parity);
// update uses G[i][j] -= col[i]*col[j]/col[k]  (LDL-style, no sqrt).
template <int CB, int CNEXT>
__device__ __forceinline__ void chol_step(const int k, const int t, const int ti, const int tj,
                                          float (&gr)[8][8], float* __restrict__ colbuf,
                                          float* __restrict__ yL, float& ld, float& yb) {
  __syncthreads();
  const int rb = (k & 1) * COLSTR;
  const float dk = colbuf[rb + k];            // broadcast
  const float inv2 = __builtin_amdgcn_rcpf(dk);
  const float yk = yL[k];                     // broadcast
  if (t == 0) { ld += 0.5f * __logf(dk); yb += yk * yk * inv2; }

  float ra[8], rc[8];
#pragma unroll
  for (int a = CB; a < 8; ++a) ra[a] = colbuf[rb + ti + 16 * a];
#pragma unroll
  for (int c = CB; c < 8; ++c) rc[c] = colbuf[rb + tj + 16 * c];
  // only the boundary group can contain dead rows/cols (i<=k or j<=k)
  ra[CB] = (ti + 16 * CB > k) ? ra[CB] : 0.0f;
  rc[CB] = (tj + 16 * CB > k) ? rc[CB] : 0.0f;
#pragma unroll
  for (int a = CB; a < 8; ++a) ra[a] *= inv2;
#pragma unroll
  for (int a = CB; a < 8; ++a)
#pragma unroll
    for (int c = CB; c < 8; ++c)
      gr[a][c] = fmaf(-ra[a], rc[c], gr[a][c]);

  // fused forward solve: z[i] -= col[i]*z[k]/d_k for i>k
  if (t < N_ROWS && t > k) yL[t] = fmaf(-(colbuf[rb + t] * inv2), yk, yL[t]);

  // owners of column k+1 export it (already updated in their registers)
  if constexpr (CNEXT < 8) {
    if (tj == ((k + 1) & 15)) {
      const int nb = ((k + 1) & 1) * COLSTR;
#pragma unroll
      for (int a = CB; a < 8; ++a) colbuf[nb + ti + 16 * a] = gr[a][CNEXT];
    }
  }
}

// ---------------- main kernel: one block per b ----------------
__global__ __launch_bounds__(256, 2) void chol_main(
    const float* __restrict__ Y, const float* __restrict__ X,
    const float* __restrict__ theta, const int* __restrict__ NNmax,
    const int* __restrict__ mPtr, const float* __restrict__ Yt,
    const float* __restrict__ Xt, const int useT, const int mMax,
    float* __restrict__ out) {
  __shared__ __align__(16) float Wl[N_ROWS * WST];
  __shared__ float colbuf[2 * COLSTR];
  __shared__ float yL[N_ROWS];
  __shared__ float swL[N_ROWS];
  __shared__ float smaskL[KW];
  __shared__ int nnL[KW];
  __shared__ int nzflag;

  const int b = blockIdx.x;
  const int t = threadIdx.x;
  const int ti = t & 15;
  const int tj = t >> 4;

  // ---- per-block scalars (redundant per thread; cheap) ----
  const float th0 = theta[0], th1 = theta[1], th2 = theta[2], th3 = theta[3], th4 = theta[4];
  const float th5 = theta[5], th6 = theta[6], th7 = theta[7], th8 = theta[8], th9 = theta[9];
  const float logs = -__logf((float)(b + 1));
  const float nug = fmaxf(__expf(th0 + th1 * logs) - 1e-5f, 0.0f) + 1e-5f;
  const float sigma = __expf(th3 + th4 * logs);
  const float sig2 = sigma * sigma;
  const float invNug = 1.0f / nug;
  const float invL2 = __expf(-2.0f * th5) * (1.0f / 3.0f);  // 1/lenScal^2, lenScal=e^th5*sqrt(3)
  const float sx0 = __expf(th6 + th8 * logs);
  const float sx1 = __expf(th7 + th9 * logs);
  int m = *mPtr; if (m > 30) m = 30;

  if (t == 0) nzflag = 0;
  if (t < KW) {
    nnL[t] = (t < m) ? NNmax[b * mMax + t] : 0;
    smaskL[t] = (t < m && t < b) ? __expf(0.5f * (float)(t + 1) * th2) : 0.0f;
  }
  __syncthreads();

  // ---- fill W (128 x 32) in LDS; column j, row i ----
  {
    const int i0 = t & 127;
    const int jb = t >> 7;
#pragma unroll
    for (int q = 0; q < 16; ++q) {
      const int j = jb + 2 * q;
      float v;
      if (j < m) {
        v = (useT ? Yt[nnL[j] * N_ROWS + i0] : Y[i0 * N_COLS + nnL[j]]) * smaskL[j];
      } else if (j < m + 2) {
        const int kc = j - m;
        v = useT ? Xt[(b * N_ROWS + i0) * 2 + kc] : X[(i0 * N_COLS + b) * 2 + kc];
        v *= (kc == 0) ? sx0 : sx1;
      } else {
        v = 0.0f;
      }
      Wl[i0 * WST + j] = v;
    }
  }
  if (t < N_ROWS) {
    const float2 xv = useT ? ((const float2*)Xt)[b * N_ROWS + t]
                           : ((const float2*)X)[t * N_COLS + b];
    if (xv.x != 0.0f || xv.y != 0.0f) atomicOr(&nzflag, 1);
    yL[t] = useT ? Yt[b * N_ROWS + t] : Y[t * N_COLS + b];
  }
  __syncthreads();
  if (nzflag == 0 && t < N_ROWS) {  // xz: zero the X part of W
    Wl[t * WST + m] = 0.0f;
    Wl[t * WST + m + 1] = 0.0f;
  }
  __syncthreads();

  // ---- Gram: gr[a][c] = W[i,:] . W[j,:]  (i=ti+16a, j=tj+16c) ----
  float gr[8][8];
#pragma unroll
  for (int a = 0; a < 8; ++a)
#pragma unroll
    for (int c = 0; c < 8; ++c) gr[a][c] = 0.0f;

#pragma unroll
  for (int kk = 0; kk < KW; kk += 4) {
    float4 wa[8], wc[8];
#pragma unroll
    for (int a = 0; a < 8; ++a) wa[a] = *(const float4*)&Wl[(ti + 16 * a) * WST + kk];
#pragma unroll
    for (int c = 0; c < 8; ++c) wc[c] = *(const float4*)&Wl[(tj + 16 * c) * WST + kk];
#pragma unroll
    for (int a = 0; a < 8; ++a)
#pragma unroll
      for (int c = 0; c < 8; ++c) {
        float acc = gr[a][c];
        acc = fmaf(wa[a].x, wc[c].x, acc);
        acc = fmaf(wa[a].y, wc[c].y, acc);
        acc = fmaf(wa[a].z, wc[c].z, acc);
        acc = fmaf(wa[a].w, wc[c].w, acc);
        gr[a][c] = acc;
      }
  }

  // diag (row sum-of-squares) to LDS
  if (ti == tj) {
#pragma unroll
    for (int a = 0; a < 8; ++a) swL[ti + 16 * a] = gr[a][a];
  }
  __syncthreads();

  // ---- transform dot -> G = I + (dot + matern*sig2)/nug ----
  if (b != 0) {
    float swa[8], swc[8];
#pragma unroll
    for (int a = 0; a < 8; ++a) swa[a] = swL[ti + 16 * a];
#pragma unroll
    for (int c = 0; c < 8; ++c) swc[c] = swL[tj + 16 * c];
#pragma unroll
    for (int a = 0; a < 8; ++a)
#pragma unroll
      for (int c = 0; c < 8; ++c) {
        const float d = gr[a][c];
        float r2 = (swa[a] + swc[c] - 2.0f * d) * invL2;
        r2 = fmaxf(r2, 0.0f);
        const float cc = sqrtf(3.0f * r2);
        const float mat = (1.0f + cc) * __expf(-cc);
        float g = fmaf(mat, sig2, d) * invNug;
        if (a == c) g += (ti == tj) ? 1.0f : 0.0f;
        gr[a][c] = g;
      }
  } else {
#pragma unroll
    for (int a = 0; a < 8; ++a)
#pragma unroll
      for (int c = 0; c < 8; ++c) gr[a][c] = (ti == tj && a == c) ? 1.0f : 0.0f;
  }

  // export column 0 (buffer 0)
  if (tj == 0) {
#pragma unroll
    for (int a = 0; a < 8; ++a) colbuf[ti + 16 * a] = gr[a][0];
  }

  // ---- fused Cholesky + forward solve + logdet: 128 steps, 1 barrier each ----
  float ld = 0.0f, yb = 0.0f;
#define CHOL_GROUP(CB)                                                        \
  {                                                                           \
    _Pragma("unroll 1") for (int kk = 0; kk < 15; ++kk)                       \
        chol_step<CB, CB>(CB * 16 + kk, t, ti, tj, gr, colbuf, yL, ld, yb);   \
    chol_step<CB, CB + 1>(CB * 16 + 15, t, ti, tj, gr, colbuf, yL, ld, yb);   \
  }
  CHOL_GROUP(0) CHOL_GROUP(1) CHOL_GROUP(2) CHOL_GROUP(3)
  CHOL_GROUP(4) CHOL_GROUP(5) CHOL_GROUP(6) CHOL_GROUP(7)
#undef CHOL_GROUP

  // ---- final reduction ----
  if (t == 0) {
    const float alpha = 2.0625f;          // (1/NUG_MULT^2)+2, theta-independent
    const float alphaPost = alpha + 64.0f;
    const float beta = 1.0625f * nug;     // nug*(alpha-1)
    const float betaPost = beta + 0.5f * yb;
    const float loglik = -ld + alpha * __logf(beta) - alphaPost * __logf(betaPost)
                       + lgammaf(alphaPost) - lgammaf(alpha);
    atomicAdd(out, -loglik);
  }
}

// ---------------- host launch ----------------
extern "C" void kernel_launch(void* const* d_in, const int* in_sizes, int n_in,
                              void* d_out, int out_size, void* d_ws, size_t ws_size,
                              hipStream_t stream) {
  const float* Y = (const float*)d_in[0];
  const float* X = (const float*)d_in[1];
  const float* theta = (const float*)d_in[2];
  const int* NNmax = (const int*)d_in[3];
  const int* mPtr = (const int*)d_in[4];
  float* out = (float*)d_out;
  const int mMax = in_sizes[3] / N_COLS;  // 64

  hipMemsetAsync(out, 0, sizeof(float) * out_size, stream);

  float* Yt = (float*)d_ws;                         // 2048*128 floats
  float* Xt = (float*)d_ws + N_COLS * N_ROWS;       // 2048*128*2 floats
  const size_t need = (size_t)(N_COLS * N_ROWS * 3) * sizeof(float);
  const int useT = (ws_size >= need) ? 1 : 0;

  if (useT) {
    dim3 tb(32, 8);
    transpose_y_kernel<<<dim3(N_COLS / 32, N_ROWS / 32), tb, 0, stream>>>(Y, Yt);
    transpose_x_kernel<<<dim3(N_COLS / 32, N_ROWS / 32), tb, 0, stream>>>(
        (const float2*)X, (float2*)Xt);
  }
  chol_main<<<N_COLS, 256, 0, stream>>>(Y, X, theta, NNmax, mPtr, Yt, Xt, useT, mMax, out);
}